// Round 7
// baseline (267.889 us; speedup 1.0000x reference)
//
#include <hip/hip_runtime.h>

// FocalLoss (RetinaNet-style) on MI355X.
// Inputs (fp32): classifications (8,49104,90), regressions (8,49104,4),
//                anchors (1,49104,4), annotations (8,32,5)
// Output: 2 fp32 scalars (clf_loss, reg_loss).
//
// R7: single kernel. Per block (256 anchors of one image):
//   phase 1: IoU match -> worklists (matched / ignored) in LDS + reg loss.
//   phase 2: unconditional base stream sum x^2*log2(1-x), 8 loads in flight,
//            two accumulators.
//   phase 3: sparse corrections from L2-hot re-reads.
//   block partial -> unique ws slot; LAST block (device-scope atomic on a
//   poisoned-0xAA counter, deterministic final value) reduces partials and
//   writes out. No separate finalize launch.

namespace {
constexpr int B_N = 8;
constexpr int A_N = 49104;
constexpr int C_N = 90;
constexpr int M_N = 32;
constexpr float EPSF   = 1e-4f;
constexpr float ACCEPT = 0.5f;
constexpr float REJECT = 0.4f;
constexpr float SL1R   = 9.0f;
constexpr float CLFW   = 1.0f;
constexpr float REGW   = 50.0f;
constexpr float LN2    = 0.69314718055994530942f;

constexpr int APB  = 256;                      // anchors per block
constexpr int NBX  = (A_N + APB - 1) / APB;    // 192 blocks per image
constexpr unsigned NBLK = (unsigned)(NBX * B_N);          // 1536
constexpr unsigned POISON = 0xAAAAAAAAu;                  // ws poison pattern
constexpr unsigned LAST_RANK = POISON + NBLK - 1u;        // no 32-bit wrap

__device__ __forceinline__ float clampx(float x) {
    return __builtin_amdgcn_fmed3f(x, EPSF, 1.0f - EPSF);
}
__device__ __forceinline__ float neg_term(float x) {   // tgt==0 focal term (ln)
    x = clampx(x);
    return 0.75f * x * x * (-__logf(1.0f - x));
}
__device__ __forceinline__ float pos_term(float x) {   // tgt==1 focal term (ln)
    x = clampx(x);
    float o = 1.0f - x;
    return 0.25f * o * o * (-__logf(x));
}
} // namespace

// grid (NBX, B), block 256.
__global__ void fused_kernel(const float* __restrict__ anchors,
                             const float* __restrict__ reg,
                             const float* __restrict__ ann,
                             const float* __restrict__ clf,
                             float4*   __restrict__ part,     // [B][NBX]
                             unsigned* __restrict__ counter,  // 1 (poisoned)
                             float*    __restrict__ out)
{
    __shared__ float sann[M_N * 5];
    __shared__ int   s_match[APB];   // (local_a << 8) | class
    __shared__ int   s_ign[APB];     // local_a
    __shared__ int   s_nm, s_ni;
    __shared__ float sred[4][4];
    __shared__ unsigned s_rank;

    const int b   = blockIdx.y;
    const int a0  = blockIdx.x * APB;
    const int tid = threadIdx.x;
    if (tid < M_N * 5) sann[tid] = ann[b * M_N * 5 + tid];
    if (tid == 0) { s_nm = 0; s_ni = 0; }
    __syncthreads();

    // ---------- phase 1: match ----------
    float cnt  = 0.0f;
    float rsum = 0.0f;
    float corr = 0.0f;
    const int i = a0 + tid;

    if (i < A_N) {
        const float4 av = ((const float4*)anchors)[i];
        const float ay1 = av.x, ax1 = av.y, ay2 = av.z, ax2 = av.w;
        const float aw = ax2 - ax1, ah = ay2 - ay1;
        const float aarea = aw * ah;

        float best = -3.4e38f;
        int   arg  = 0;
        #pragma unroll 8
        for (int j = 0; j < M_N; ++j) {
            const float bx1 = sann[j*5+0], by1 = sann[j*5+1];
            const float bx2 = sann[j*5+2], by2 = sann[j*5+3];
            const float lb  = sann[j*5+4];
            float iw = fminf(ax2, bx2) - fmaxf(ax1, bx1); iw = fmaxf(iw, 0.0f);
            float ih = fminf(ay2, by2) - fmaxf(ay1, by1); ih = fmaxf(ih, 0.0f);
            const float inter = iw * ih;
            const float barea = (bx2 - bx1) * (by2 - by1);
            const float uni   = fmaxf(aarea + barea - inter, 1e-8f);
            float iou = inter / uni;
            if (lb == -1.0f) iou = -1.0f;
            if (iou > best) { best = iou; arg = j; } // first-occurrence argmax
        }

        const bool matched   = best > ACCEPT;
        const bool unmatched = best < REJECT;

        if (matched) {
            const int s = (int)sann[arg*5+4] - 1;   // class 0..89
            cnt = 1.0f;
            const int slot = atomicAdd(&s_nm, 1);
            s_match[slot] = (tid << 8) | s;
            const float bx1 = sann[arg*5+0], by1 = sann[arg*5+1];
            const float bx2 = sann[arg*5+2], by2 = sann[arg*5+3];
            const float gwr = bx2 - bx1, ghr = by2 - by1;
            const float gcx = bx1 + 0.5f * gwr, gcy = by1 + 0.5f * ghr;
            const float gw  = fmaxf(gwr, 1.0f), gh = fmaxf(ghr, 1.0f);
            const float acx = ax1 + 0.5f * aw, acy = ay1 + 0.5f * ah;
            const float t0 = (gcy - acy) / ah;
            const float t1 = (gcx - acx) / aw;
            const float t2 = __logf(gh / ah);
            const float t3 = __logf(gw / aw);
            const float4 rv = ((const float4*)reg)[b * A_N + i];
            float d;
            d = fabsf(SL1R * (rv.x - t0)); rsum += (d < 1.0f) ? 0.5f*d*d : d - 0.5f;
            d = fabsf(SL1R * (rv.y - t1)); rsum += (d < 1.0f) ? 0.5f*d*d : d - 0.5f;
            d = fabsf(SL1R * (rv.z - t2)); rsum += (d < 1.0f) ? 0.5f*d*d : d - 0.5f;
            d = fabsf(SL1R * (rv.w - t3)); rsum += (d < 1.0f) ? 0.5f*d*d : d - 0.5f;
        } else if (!unmatched) {
            const int slot = atomicAdd(&s_ni, 1);
            s_ign[slot] = tid;
        }
    }
    __syncthreads();

    // ---------- phase 2: unconditional base stream ----------
    const int nA  = min(APB, A_N - a0);
    const int nF4 = nA * C_N / 4;                 // 5760 full, 4680 last
    const float4* __restrict__ p =
        (const float4*)(clf + ((size_t)b * A_N + a0) * C_N);

    float S0 = 0.0f, S1 = 0.0f;

    auto w4 = [](float4 v) -> float {
        float s = 0.0f;
        const float x0 = clampx(v.x), x1 = clampx(v.y);
        const float x2 = clampx(v.z), x3 = clampx(v.w);
        s = fmaf(x0 * x0, __log2f(1.0f - x0), s);
        s = fmaf(x1 * x1, __log2f(1.0f - x1), s);
        s = fmaf(x2 * x2, __log2f(1.0f - x2), s);
        s = fmaf(x3 * x3, __log2f(1.0f - x3), s);
        return s;
    };

    int f = tid;
    #pragma unroll 1
    for (; f + 1792 < nF4; f += 2048) {           // 8 loads in flight
        const float4 v0 = p[f];
        const float4 v1 = p[f + 256];
        const float4 v2 = p[f + 512];
        const float4 v3 = p[f + 768];
        const float4 v4 = p[f + 1024];
        const float4 v5 = p[f + 1280];
        const float4 v6 = p[f + 1536];
        const float4 v7 = p[f + 1792];
        S0 += w4(v0) + w4(v2) + w4(v4) + w4(v6);
        S1 += w4(v1) + w4(v3) + w4(v5) + w4(v7);
    }
    #pragma unroll 1
    for (; f + 768 < nF4; f += 1024) {            // 4 in flight
        const float4 v0 = p[f];
        const float4 v1 = p[f + 256];
        const float4 v2 = p[f + 512];
        const float4 v3 = p[f + 768];
        S0 += w4(v0) + w4(v2);
        S1 += w4(v1) + w4(v3);
    }
    #pragma unroll 1
    for (; f < nF4; f += 256) S0 += w4(p[f]);
    float S = S0 + S1;

    // ---------- phase 3: sparse corrections (rows are L1/L2-hot) ----------
    const int nm = s_nm, ni = s_ni;
    for (int k = tid; k < nm; k += 256) {
        const int packed = s_match[k];
        const int a  = packed >> 8;
        const int sc = packed & 0xFF;
        const float x = clf[((size_t)b * A_N + a0 + a) * C_N + sc];
        corr += pos_term(x) - neg_term(x);
    }
    const int wid  = tid >> 6;
    const int lane = tid & 63;
    for (int e = wid; e < ni; e += 4) {           // one wave per ignored row
        const int a = s_ign[e];
        const float2* __restrict__ r2 =
            (const float2*)(clf + ((size_t)b * A_N + a0 + a) * C_N);
        if (lane < 45) {                          // 45 lanes x float2 = 90 elems
            const float2 u = r2[lane];
            corr -= neg_term(u.x) + neg_term(u.y);
        }
    }

    // ---------- block reduce, one ws write ----------
    #pragma unroll
    for (int off = 32; off > 0; off >>= 1) {
        cnt  += __shfl_down(cnt,  off);
        rsum += __shfl_down(rsum, off);
        S    += __shfl_down(S,    off);
        corr += __shfl_down(corr, off);
    }
    if (lane == 0) {
        sred[wid][0] = cnt; sred[wid][1] = rsum;
        sred[wid][2] = S;   sred[wid][3] = corr;
    }
    __syncthreads();
    if (tid == 0) {
        float c = 0.f, r = 0.f, ss = 0.f, k = 0.f;
        #pragma unroll
        for (int w = 0; w < 4; ++w) {
            c += sred[w][0]; r += sred[w][1]; ss += sred[w][2]; k += sred[w][3];
        }
        part[b * NBX + blockIdx.x] = make_float4(c, r, ss, k);
        __threadfence();                      // release part[] device-wide
        s_rank = atomicAdd(counter, 1u);      // device-scope by default
    }
    __syncthreads();

    // ---------- last block: finalize ----------
    if (s_rank == LAST_RANK) {
        __threadfence();                      // acquire all part[] writes
        __shared__ float t_cnt[B_N], t_rsum[B_N], t_S[B_N], t_corr[B_N];
        const int fb = tid >> 5;              // image
        const int fj = tid & 31;
        float fc = 0.f, fr = 0.f, fS = 0.f, fk = 0.f;
        #pragma unroll
        for (int k = 0; k < NBX / 32; ++k) {  // 6 slots
            const float4 m = part[fb * NBX + fj + 32 * k];
            fc += m.x; fr += m.y; fS += m.z; fk += m.w;
        }
        #pragma unroll
        for (int off = 16; off > 0; off >>= 1) {
            fc += __shfl_down(fc, off, 32);
            fr += __shfl_down(fr, off, 32);
            fS += __shfl_down(fS, off, 32);
            fk += __shfl_down(fk, off, 32);
        }
        if (fj == 0) { t_cnt[fb] = fc; t_rsum[fb] = fr; t_S[fb] = fS; t_corr[fb] = fk; }
        __syncthreads();
        if (tid == 0) {
            float cl = 0.0f, rl = 0.0f;
            #pragma unroll
            for (int bb = 0; bb < B_N; ++bb) {
                const float n = t_cnt[bb];
                const float clf_total = -0.75f * LN2 * t_S[bb] + t_corr[bb];
                cl += clf_total / fmaxf(1.0f, n);
                if (n > 0.0f) rl += t_rsum[bb] / (4.0f * n);
            }
            out[0] = CLFW * (cl / (float)B_N);
            out[1] = REGW * (rl / (float)B_N);
        }
    }
}

extern "C" void kernel_launch(void* const* d_in, const int* in_sizes, int n_in,
                              void* d_out, int out_size, void* d_ws, size_t ws_size,
                              hipStream_t stream) {
    const float* clf     = (const float*)d_in[0];
    const float* reg     = (const float*)d_in[1];
    const float* anchors = (const float*)d_in[2];
    const float* ann     = (const float*)d_in[3];
    float* out = (float*)d_out;

    float4*   part    = (float4*)d_ws;                       // 1536 slots
    unsigned* counter = (unsigned*)((char*)d_ws + NBLK * sizeof(float4));
    // counter is re-poisoned to 0xAAAAAAAA before every launch; LAST_RANK
    // accounts for that — no memset needed.

    dim3 grid(NBX, B_N);
    fused_kernel<<<grid, 256, 0, stream>>>(anchors, reg, ann, clf,
                                           part, counter, out);
}

// Round 8
// 215.227 us; speedup vs baseline: 1.2447x; 1.2447x over previous
//
#include <hip/hip_runtime.h>

// FocalLoss (RetinaNet-style) on MI355X.
// Inputs (fp32): classifications (8,49104,90), regressions (8,49104,4),
//                anchors (1,49104,4), annotations (8,32,5)
// Output: 2 fp32 scalars (clf_loss, reg_loss).
//
// R8: ONE compute kernel with block specialization (no device-scope sync —
// R7's per-block __threadfence + same-address atomics cost +45us):
//   blocks x<192:  match blocks — IoU match for 256 anchors, reg smooth-L1,
//                  sparse clf corrections (matched element pos-neg, ignored
//                  rows -neg-sum). Runs concurrently with the stream.
//   blocks x>=192: stream blocks — unconditional sum x^2*log2(1-x) over a
//                  contiguous 2158-float4 chunk, one straight-line 8-deep
//                  batch per thread.
// Block partials -> unique ws slots. Small finalize launch reduces (kernel
// boundary is the fence).

namespace {
constexpr int B_N = 8;
constexpr int A_N = 49104;
constexpr int C_N = 90;
constexpr int M_N = 32;
constexpr float EPSF   = 1e-4f;
constexpr float ACCEPT = 0.5f;
constexpr float REJECT = 0.4f;
constexpr float SL1R   = 9.0f;
constexpr float CLFW   = 1.0f;
constexpr float REGW   = 50.0f;
constexpr float LN2    = 0.69314718055994530942f;

constexpr int APB  = 256;                       // anchors per match block
constexpr int MBX  = (A_N + APB - 1) / APB;     // 192 match blocks / image
constexpr int SBX  = 512;                       // stream blocks / image
constexpr int IMG_F4 = A_N * C_N / 4;           // 1,104,840 float4 / image
constexpr int CHUNK  = (IMG_F4 + SBX - 1) / SBX;// 2158 float4 / stream block

// part layout: [0, MBX*B)            match slots  (cnt, rsum, 0, corr)
//              [MBX*B, MBX*B+SBX*B)  stream slots (0, 0, S, 0)
constexpr int MSLOTS = MBX * B_N;               // 1536
constexpr int SSLOT0 = MSLOTS;

__device__ __forceinline__ float clampx(float x) {
    return __builtin_amdgcn_fmed3f(x, EPSF, 1.0f - EPSF);
}
__device__ __forceinline__ float neg_term(float x) {   // tgt==0 focal term (ln)
    x = clampx(x);
    return 0.75f * x * x * (-__logf(1.0f - x));
}
__device__ __forceinline__ float pos_term(float x) {   // tgt==1 focal term (ln)
    x = clampx(x);
    float o = 1.0f - x;
    return 0.25f * o * o * (-__logf(x));
}
} // namespace

// grid (MBX + SBX, B), block 256.
__global__ void __launch_bounds__(256, 8)
fused_kernel(const float* __restrict__ anchors,
             const float* __restrict__ reg,
             const float* __restrict__ ann,
             const float* __restrict__ clf,
             float4* __restrict__ part)
{
    __shared__ float sann[M_N * 5];
    __shared__ int   s_match[APB];   // (local_a << 8) | class
    __shared__ int   s_ign[APB];     // local_a
    __shared__ int   s_nm, s_ni;
    __shared__ float sred[4][4];

    const int b   = blockIdx.y;
    const int tid = threadIdx.x;
    const int wid  = tid >> 6;
    const int lane = tid & 63;

    if (blockIdx.x >= MBX) {
        // ================= stream block =================
        const int sx    = blockIdx.x - MBX;
        const int fbase = sx * CHUNK;
        const int n     = min(CHUNK, IMG_F4 - fbase);   // 2158 or 2102 (last)
        const float4* __restrict__ p =
            (const float4*)(clf + (size_t)b * (A_N * C_N)) + fbase;

        auto w4 = [](float4 v) -> float {
            float s = 0.0f;
            const float x0 = clampx(v.x), x1 = clampx(v.y);
            const float x2 = clampx(v.z), x3 = clampx(v.w);
            s = fmaf(x0 * x0, __log2f(1.0f - x0), s);
            s = fmaf(x1 * x1, __log2f(1.0f - x1), s);
            s = fmaf(x2 * x2, __log2f(1.0f - x2), s);
            s = fmaf(x3 * x3, __log2f(1.0f - x3), s);
            return s;
        };

        float S0 = 0.0f, S1 = 0.0f;
        int f = tid;
        #pragma unroll 1
        for (; f + 1792 < n; f += 2048) {       // one straight-line 8-deep batch
            const float4 v0 = p[f];
            const float4 v1 = p[f + 256];
            const float4 v2 = p[f + 512];
            const float4 v3 = p[f + 768];
            const float4 v4 = p[f + 1024];
            const float4 v5 = p[f + 1280];
            const float4 v6 = p[f + 1536];
            const float4 v7 = p[f + 1792];
            S0 += w4(v0) + w4(v2) + w4(v4) + w4(v6);
            S1 += w4(v1) + w4(v3) + w4(v5) + w4(v7);
        }
        #pragma unroll 1
        for (; f < n; f += 256) S0 += w4(p[f]); // <=1 scalar tail iter
        float S = S0 + S1;

        #pragma unroll
        for (int off = 32; off > 0; off >>= 1) S += __shfl_down(S, off);
        if (lane == 0) sred[wid][0] = S;
        __syncthreads();
        if (tid == 0) {
            part[SSLOT0 + b * SBX + sx] =
                make_float4(0.f, 0.f, sred[0][0] + sred[1][0] + sred[2][0] + sred[3][0], 0.f);
        }
        return;
    }

    // ================= match block =================
    const int a0 = blockIdx.x * APB;
    if (tid < M_N * 5) sann[tid] = ann[b * M_N * 5 + tid];
    if (tid == 0) { s_nm = 0; s_ni = 0; }
    __syncthreads();

    float cnt  = 0.0f;
    float rsum = 0.0f;
    float corr = 0.0f;
    const int i = a0 + tid;

    if (i < A_N) {
        const float4 av = ((const float4*)anchors)[i];
        const float ay1 = av.x, ax1 = av.y, ay2 = av.z, ax2 = av.w;
        const float aw = ax2 - ax1, ah = ay2 - ay1;
        const float aarea = aw * ah;

        float best = -3.4e38f;
        int   arg  = 0;
        #pragma unroll 8
        for (int j = 0; j < M_N; ++j) {
            const float bx1 = sann[j*5+0], by1 = sann[j*5+1];
            const float bx2 = sann[j*5+2], by2 = sann[j*5+3];
            const float lb  = sann[j*5+4];
            float iw = fminf(ax2, bx2) - fmaxf(ax1, bx1); iw = fmaxf(iw, 0.0f);
            float ih = fminf(ay2, by2) - fmaxf(ay1, by1); ih = fmaxf(ih, 0.0f);
            const float inter = iw * ih;
            const float barea = (bx2 - bx1) * (by2 - by1);
            const float uni   = fmaxf(aarea + barea - inter, 1e-8f);
            float iou = inter / uni;
            if (lb == -1.0f) iou = -1.0f;
            if (iou > best) { best = iou; arg = j; } // first-occurrence argmax
        }

        const bool matched   = best > ACCEPT;
        const bool unmatched = best < REJECT;

        if (matched) {
            const int s = (int)sann[arg*5+4] - 1;   // class 0..89
            cnt = 1.0f;
            const int slot = atomicAdd(&s_nm, 1);
            s_match[slot] = (tid << 8) | s;
            const float bx1 = sann[arg*5+0], by1 = sann[arg*5+1];
            const float bx2 = sann[arg*5+2], by2 = sann[arg*5+3];
            const float gwr = bx2 - bx1, ghr = by2 - by1;
            const float gcx = bx1 + 0.5f * gwr, gcy = by1 + 0.5f * ghr;
            const float gw  = fmaxf(gwr, 1.0f), gh = fmaxf(ghr, 1.0f);
            const float acx = ax1 + 0.5f * aw, acy = ay1 + 0.5f * ah;
            const float t0 = (gcy - acy) / ah;
            const float t1 = (gcx - acx) / aw;
            const float t2 = __logf(gh / ah);
            const float t3 = __logf(gw / aw);
            const float4 rv = ((const float4*)reg)[b * A_N + i];
            float d;
            d = fabsf(SL1R * (rv.x - t0)); rsum += (d < 1.0f) ? 0.5f*d*d : d - 0.5f;
            d = fabsf(SL1R * (rv.y - t1)); rsum += (d < 1.0f) ? 0.5f*d*d : d - 0.5f;
            d = fabsf(SL1R * (rv.z - t2)); rsum += (d < 1.0f) ? 0.5f*d*d : d - 0.5f;
            d = fabsf(SL1R * (rv.w - t3)); rsum += (d < 1.0f) ? 0.5f*d*d : d - 0.5f;
        } else if (!unmatched) {
            const int slot = atomicAdd(&s_ni, 1);
            s_ign[slot] = tid;
        }
    }
    __syncthreads();

    // sparse clf corrections
    const int nm = s_nm, ni = s_ni;
    for (int k = tid; k < nm; k += 256) {
        const int packed = s_match[k];
        const int a  = packed >> 8;
        const int sc = packed & 0xFF;
        const float x = clf[((size_t)b * A_N + a0 + a) * C_N + sc];
        corr += pos_term(x) - neg_term(x);
    }
    for (int e = wid; e < ni; e += 4) {           // one wave per ignored row
        const int a = s_ign[e];
        const float2* __restrict__ r2 =
            (const float2*)(clf + ((size_t)b * A_N + a0 + a) * C_N);
        if (lane < 45) {                          // 45 lanes x float2 = 90 elems
            const float2 u = r2[lane];
            corr -= neg_term(u.x) + neg_term(u.y);
        }
    }

    #pragma unroll
    for (int off = 32; off > 0; off >>= 1) {
        cnt  += __shfl_down(cnt,  off);
        rsum += __shfl_down(rsum, off);
        corr += __shfl_down(corr, off);
    }
    if (lane == 0) {
        sred[wid][0] = cnt; sred[wid][1] = rsum; sred[wid][2] = corr;
    }
    __syncthreads();
    if (tid == 0) {
        float c = 0.f, r = 0.f, k = 0.f;
        #pragma unroll
        for (int w = 0; w < 4; ++w) { c += sred[w][0]; r += sred[w][1]; k += sred[w][2]; }
        part[b * MBX + blockIdx.x] = make_float4(c, r, 0.f, k);
    }
}

// ---------------- finalize: 1 block, 256 threads ----------------
// threads b*32..b*32+31 reduce image b's 192 match + 512 stream slots.
__global__ void finalize_kernel(const float4* __restrict__ part,
                                float*        __restrict__ out)
{
    __shared__ float s_cnt[B_N], s_rsum[B_N], s_S[B_N], s_corr[B_N];
    const int tid = threadIdx.x;
    const int b   = tid >> 5;
    const int j   = tid & 31;

    float cnt = 0.f, rsum = 0.f, S = 0.f, corr = 0.f;
    #pragma unroll
    for (int k = 0; k < MBX / 32; ++k) {            // 6 match slots
        const float4 m = part[b * MBX + j + 32 * k];
        cnt += m.x; rsum += m.y; corr += m.w;
    }
    #pragma unroll
    for (int k = 0; k < SBX / 32; ++k) {            // 16 stream slots
        const float4 m = part[SSLOT0 + b * SBX + j + 32 * k];
        S += m.z;
    }
    #pragma unroll
    for (int off = 16; off > 0; off >>= 1) {
        cnt  += __shfl_down(cnt,  off, 32);
        rsum += __shfl_down(rsum, off, 32);
        S    += __shfl_down(S,    off, 32);
        corr += __shfl_down(corr, off, 32);
    }
    if (j == 0) { s_cnt[b] = cnt; s_rsum[b] = rsum; s_S[b] = S; s_corr[b] = corr; }
    __syncthreads();
    if (tid == 0) {
        float cl = 0.0f, rl = 0.0f;
        #pragma unroll
        for (int bb = 0; bb < B_N; ++bb) {
            const float n = s_cnt[bb];
            const float clf_total = -0.75f * LN2 * s_S[bb] + s_corr[bb];
            cl += clf_total / fmaxf(1.0f, n);
            if (n > 0.0f) rl += s_rsum[bb] / (4.0f * n);
        }
        out[0] = CLFW * (cl / (float)B_N);
        out[1] = REGW * (rl / (float)B_N);
    }
}

extern "C" void kernel_launch(void* const* d_in, const int* in_sizes, int n_in,
                              void* d_out, int out_size, void* d_ws, size_t ws_size,
                              hipStream_t stream) {
    const float* clf     = (const float*)d_in[0];
    const float* reg     = (const float*)d_in[1];
    const float* anchors = (const float*)d_in[2];
    const float* ann     = (const float*)d_in[3];
    float*  out  = (float*)d_out;
    float4* part = (float4*)d_ws;   // 1536 + 4096 slots, all written each launch

    {
        dim3 grid(MBX + SBX, B_N);
        fused_kernel<<<grid, 256, 0, stream>>>(anchors, reg, ann, clf, part);
    }
    finalize_kernel<<<1, 256, 0, stream>>>(part, out);
}